// Round 1
// baseline (69.178 us; speedup 1.0000x reference)
//
#include <hip/hip_runtime.h>

// Grouped conv1d (kernel=3, pad=1) over last dim with circular input shift
// (+1 along axis 3) and circular output shift (+1 along axis 2).
// x: (128, 56, 56) fp32, W: (64, 16, 3) fp32, out: (32, 56, 56) fp32.
//
// y[o,k,n,m] = sum_{i,j} tp[o*64+i, n, m+j] * W[i,k,j]
//   tp[., p] = x[., (p-2) mod 56] for p in [1,56], 0 for p in {0,57}
// out[(o*16+k), (n+1) mod 56, m] = y[o,k,n,m]

#define HDIM 56
#define WDIM 56
#define HW   (HDIM * WDIM)      // 3136
#define GI   64                 // input channels per group
#define KOUT 16                 // output channels per group
#define PADW 58                 // padded row width

__global__ __launch_bounds__(128) void shift_conv_kernel(
    const float* __restrict__ x, const float* __restrict__ Wg,
    float* __restrict__ out)
{
    __shared__ float xs[GI * PADW];   // 64 x 58 = 14.8 KB

    const int n  = blockIdx.x;   // input H row
    const int o  = blockIdx.y;   // channel group (0,1)
    const int kh = blockIdx.z;   // k half (0,1)

    const int tx  = threadIdx.x; // 0..63
    const int ty  = threadIdx.y; // 0..1
    const int tid = ty * 64 + tx;

    // ---- stage rolled + padded row into LDS: xs[i*58 + p] = tp[o*64+i, n, p]
    const float* xbase = x + (o * GI) * HW + n * WDIM;
    for (int idx = tid; idx < GI * PADW; idx += 128) {
        int i = idx / PADW;
        int p = idx - i * PADW;
        float v = 0.0f;
        if (p >= 1 && p <= WDIM) {
            int q = (p >= 2) ? (p - 2) : (p + WDIM - 2);  // (p-2) mod 56
            v = xbase[i * HW + q];
        }
        xs[idx] = v;
    }
    __syncthreads();

    // wave-uniform k0 (blockDim.x == 64 -> one ty per wave) => scalar W loads
    int k0 = kh * 8 + ty * 4;
    k0 = __builtin_amdgcn_readfirstlane(k0);

    const int m = (tx < WDIM) ? tx : (WDIM - 1);  // clamp idle lanes (safe LDS reads)

    float acc0 = 0.f, acc1 = 0.f, acc2 = 0.f, acc3 = 0.f;
    const float* wk = Wg + k0 * 3;   // 12 contiguous floats per i: k0..k0+3, j=0..2

    #pragma unroll 4
    for (int i = 0; i < GI; ++i) {
        float a0 = xs[i * PADW + m];
        float a1 = xs[i * PADW + m + 1];
        float a2 = xs[i * PADW + m + 2];
        const float* w = wk + i * (KOUT * 3);
        acc0 = fmaf(a2, w[2],  fmaf(a1, w[1],  fmaf(a0, w[0],  acc0)));
        acc1 = fmaf(a2, w[5],  fmaf(a1, w[4],  fmaf(a0, w[3],  acc1)));
        acc2 = fmaf(a2, w[8],  fmaf(a1, w[7],  fmaf(a0, w[6],  acc2)));
        acc3 = fmaf(a2, w[11], fmaf(a1, w[10], fmaf(a0, w[9],  acc3)));
    }

    if (tx < WDIM) {
        const int n1 = (n == HDIM - 1) ? 0 : (n + 1);  // output roll along H
        float* ob = out + ((o * KOUT + k0) * HDIM + n1) * WDIM + tx;
        ob[0]      = acc0;
        ob[HW]     = acc1;
        ob[2 * HW] = acc2;
        ob[3 * HW] = acc3;
    }
}

extern "C" void kernel_launch(void* const* d_in, const int* in_sizes, int n_in,
                              void* d_out, int out_size, void* d_ws, size_t ws_size,
                              hipStream_t stream) {
    const float* x  = (const float*)d_in[0];   // 128*56*56
    const float* Wg = (const float*)d_in[1];   // 64*16*3
    float* out      = (float*)d_out;           // 32*56*56

    dim3 grid(HDIM, 2, 2);   // (n, o, k-half) = 224 blocks
    dim3 block(64, 2, 1);    // 2 waves
    hipLaunchKernelGGL(shift_conv_kernel, grid, block, 0, stream, x, Wg, out);
}

// Round 2
// 62.556 us; speedup vs baseline: 1.1058x; 1.1058x over previous
//
#include <hip/hip_runtime.h>

// Grouped conv1d (kernel=3, pad=1) over last dim with circular input shift
// (+1 along axis 3) and circular output shift (+1 along axis 2).
// x: (128, 56, 56) fp32, W: (64, 16, 3) fp32, out: (32, 56, 56) fp32.
//
// y[o,k,n,m] = sum_{i,j} tp[o*64+i, n, m+j] * W[i,k,j]
//   tp[., p] = 0 if p==0 or p==57, else x[., (p-2) mod 56]
// out[(o*16+k), (n+1) mod 56, m] = y[o,k,n,m]
//
// LDS layout: x rows stored VERBATIM (no shift) at stride 60 (16B-aligned),
// column 56 is an always-zero slot. The roll+pad becomes 3 per-thread column
// indices:
//   a0 = tp[m]   -> col c0 = (m==0)  ? 56 : (m-2) mod 56
//   a1 = tp[m+1] -> col c1 = (m-1) mod 56            (never pad)
//   a2 = tp[m+2] -> col c2 = (m==55) ? 56 : m

#define HDIM 56
#define WDIM 56
#define HW   (HDIM * WDIM)      // 3136
#define GI   64                 // input channels per group
#define KOUT 16                 // output channels per group
#define LPAD 60                 // LDS row stride (floats), 240B = 16B-aligned

__global__ __launch_bounds__(128) void shift_conv_kernel(
    const float* __restrict__ x, const float* __restrict__ Wg,
    float* __restrict__ out)
{
    __shared__ float xs[GI * LPAD];   // 64 x 60 x 4B = 15 KB

    const int n  = blockIdx.x;   // input H row
    const int o  = blockIdx.y;   // channel group (0,1)
    const int kh = blockIdx.z;   // k half (0,1)

    const int tx  = threadIdx.x; // 0..63
    const int ty  = threadIdx.y; // 0..1
    const int tid = ty * 64 + tx;

    // ---- stage: 64 rows x 14 float4 = 896 vec4 loads, 7 per thread, branchless
    const float* xbase = x + (o * GI) * HW + n * WDIM;
    #pragma unroll
    for (int s = 0; s < 7; ++s) {
        int idx = tid + s * 128;          // 0..895
        int i   = idx / 14;               // row (magic-mul)
        int t4  = idx - i * 14;           // float4 within row
        float4 v = *(const float4*)(xbase + i * HW + 4 * t4);
        *(float4*)(&xs[i * LPAD + 4 * t4]) = v;
    }
    if (tid < GI) {                       // zero slot (cols 56..59)
        *(float4*)(&xs[tid * LPAD + WDIM]) = make_float4(0.f, 0.f, 0.f, 0.f);
    }
    __syncthreads();

    // wave-uniform k0 (blockDim.x == 64 -> one ty per wave) => scalar W loads.
    // k0*3 floats = k0*12 bytes in {0,48,96,144}: all 16B-aligned -> s_load_dwordx4
    int k0 = kh * 8 + ty * 4;
    k0 = __builtin_amdgcn_readfirstlane(k0);

    const int m  = (tx < WDIM) ? tx : (WDIM - 1);     // clamp idle lanes
    const int c1 = (m + 55) % 56;
    const int c0 = (m == 0)  ? 56 : (m + 54) % 56;
    const int c2 = (m == 55) ? 56 : m;

    float acc0 = 0.f, acc1 = 0.f, acc2 = 0.f, acc3 = 0.f;
    const float* wk = Wg + k0 * 3;   // 12 contiguous floats per i

    #pragma unroll 8
    for (int i = 0; i < GI; ++i) {
        float a0 = xs[i * LPAD + c0];
        float a1 = xs[i * LPAD + c1];
        float a2 = xs[i * LPAD + c2];
        const float* w = wk + i * (KOUT * 3);
        acc0 = fmaf(a2, w[2],  fmaf(a1, w[1],  fmaf(a0, w[0],  acc0)));
        acc1 = fmaf(a2, w[5],  fmaf(a1, w[4],  fmaf(a0, w[3],  acc1)));
        acc2 = fmaf(a2, w[8],  fmaf(a1, w[7],  fmaf(a0, w[6],  acc2)));
        acc3 = fmaf(a2, w[11], fmaf(a1, w[10], fmaf(a0, w[9],  acc3)));
    }

    if (tx < WDIM) {
        const int n1 = (n == HDIM - 1) ? 0 : (n + 1);  // output roll along H
        float* ob = out + ((o * KOUT + k0) * HDIM + n1) * WDIM + tx;
        ob[0]      = acc0;
        ob[HW]     = acc1;
        ob[2 * HW] = acc2;
        ob[3 * HW] = acc3;
    }
}

extern "C" void kernel_launch(void* const* d_in, const int* in_sizes, int n_in,
                              void* d_out, int out_size, void* d_ws, size_t ws_size,
                              hipStream_t stream) {
    const float* x  = (const float*)d_in[0];   // 128*56*56
    const float* Wg = (const float*)d_in[1];   // 64*16*3
    float* out      = (float*)d_out;           // 32*56*56

    dim3 grid(HDIM, 2, 2);   // (n, o, k-half) = 224 blocks
    dim3 block(64, 2, 1);    // 2 waves
    hipLaunchKernelGGL(shift_conv_kernel, grid, block, 0, stream, x, Wg, out);
}